// Round 6
// baseline (24999.828 us; speedup 1.0000x reference)
//
#include <hip/hip_runtime.h>

// LIF layer: Wx = x @ W^T (f64 VALU FMA), then scan over T. B=64,T=1000,I=1024,H=1024.
// R6: f64 MFMA abandoned (R5 diagnostic: instruction executes but yields wrong
//     values on gfx950; FP64-matrix spec rate == vector rate, same as removed
//     FP32 MFMA). VALU GEMM upgraded: TK=8 double-buffered LDS + register
//     prefetch, ONE barrier per k-tile, loads issued a full compute-block ahead
//     (~4096 CU-cyc of cover vs ~900 cyc HBM latency). FMA payload/epilogue are
//     the R2 kernel verbatim (absmax 0.0 pedigree). LDS = 33,280 B -> 2 blk/CU.

#define TM 128
#define TN 128
#define TK 8
#define PAD 2   // row stride 130 doubles; fragment b128 reads stay 16B-aligned

__global__ __launch_bounds__(256, 2) void gemm_f64_valu(
    const float* __restrict__ A,   // [M,K] row-major (x chunk)
    const float* __restrict__ B,   // [N,K] row-major (W)
    double* __restrict__ C,        // [M,N] f64
    int M, int N, int K)
{
    __shared__ double As[2][TK][TM + PAD];   // 16,640 B
    __shared__ double Bs[2][TK][TN + PAD];   // 16,640 B -> 33,280 B total

    const int tid = threadIdx.x;
    const int tx = tid & 15;
    const int ty = tid >> 4;
    const int tm = blockIdx.y * TM;
    const int tn = blockIdx.x * TN;

    // staging: one float4 per matrix per thread: row r, k-quad kq
    const int kq = (tid & 1) * 4;   // 0 or 4
    const int r  = tid >> 1;        // 0..127

    double acc[8][8];
    #pragma unroll
    for (int i = 0; i < 8; i++)
        #pragma unroll
        for (int j = 0; j < 8; j++) acc[i][j] = 0.0;

    const int ar = min(tm + r, M - 1);   // tail-block guard (loads only)
    const float* Ap = A + (size_t)ar * K + kq;
    const float* Bp = B + (size_t)(tn + r) * K + kq;

    // ---- prologue: stage 0 into buf 0 ----
    {
        const float4 a0 = *(const float4*)(Ap);
        const float4 b0 = *(const float4*)(Bp);
        As[0][kq + 0][r] = (double)a0.x; As[0][kq + 1][r] = (double)a0.y;
        As[0][kq + 2][r] = (double)a0.z; As[0][kq + 3][r] = (double)a0.w;
        Bs[0][kq + 0][r] = (double)b0.x; Bs[0][kq + 1][r] = (double)b0.y;
        Bs[0][kq + 2][r] = (double)b0.z; Bs[0][kq + 3][r] = (double)b0.w;
    }
    __syncthreads();

    const int NS = K / TK;   // 128 stages
    for (int s = 0; s < NS; ++s) {
        const int p = s & 1;
        const bool more = (s + 1) < NS;

        // issue next tile's global loads; latency hides behind the FMA block
        float4 na, nb;
        if (more) {
            const int ko = (s + 1) * TK;
            na = *(const float4*)(Ap + ko);
            nb = *(const float4*)(Bp + ko);
        }

        #pragma unroll
        for (int kk = 0; kk < TK; kk++) {
            double av[8], bv[8];
            #pragma unroll
            for (int i = 0; i < 4; i++) {
                av[2 * i]     = As[p][kk][2 * ty + 32 * i];      // pair ->
                av[2 * i + 1] = As[p][kk][2 * ty + 32 * i + 1];  //  ds_read_b128
            }
            #pragma unroll
            for (int j = 0; j < 4; j++) {
                bv[2 * j]     = Bs[p][kk][2 * tx + 32 * j];
                bv[2 * j + 1] = Bs[p][kk][2 * tx + 32 * j + 1];
            }
            #pragma unroll
            for (int i = 0; i < 8; i++)
                #pragma unroll
                for (int j = 0; j < 8; j++)
                    acc[i][j] = fma(av[i], bv[j], acc[i][j]);
        }

        // write next tile into the other buffer (last read before prev barrier)
        if (more) {
            const int q = 1 - p;
            As[q][kq + 0][r] = (double)na.x; As[q][kq + 1][r] = (double)na.y;
            As[q][kq + 2][r] = (double)na.z; As[q][kq + 3][r] = (double)na.w;
            Bs[q][kq + 0][r] = (double)nb.x; Bs[q][kq + 1][r] = (double)nb.y;
            Bs[q][kq + 2][r] = (double)nb.z; Bs[q][kq + 3][r] = (double)nb.w;
        }
        __syncthreads();
    }

    #pragma unroll
    for (int i = 0; i < 8; i++) {
        const int m = tm + 2 * ty + 32 * (i >> 1) + (i & 1);
        if (m < M) {
            double* Cr = C + (size_t)m * N + tn;
            #pragma unroll
            for (int j = 0; j < 8; j++)
                Cr[2 * tx + 32 * (j >> 1) + (j & 1)] = acc[i][j];
        }
    }
}

__global__ __launch_bounds__(256) void lif_scan_kernel(
    const double* __restrict__ Wx,  // [Bc, T, H] chunk
    const float* __restrict__ alpha,
    const float* __restrict__ u0,
    const float* __restrict__ s0,
    float* __restrict__ out,        // full [B, T, H]
    int b0, int T, int H)
{
    const int idx = blockIdx.x * blockDim.x + threadIdx.x;
    const int h  = idx & 1023;      // H = 1024
    const int bl = idx >> 10;
    const int b  = b0 + bl;

    const double AMIN = 0.8187307530779818;   // exp(-1/5)
    const double AMAX = 0.9607894391523232;   // exp(-1/25)
    double a = (double)alpha[h];
    a = fmin(fmax(a, AMIN), AMAX);
    const double oma = 1.0 - a;

    double u = (double)u0[(size_t)b * H + h];
    double s = (double)s0[(size_t)b * H + h];

    const double* wp = Wx + (size_t)bl * T * H + h;
    float* op = out + (size_t)b * T * H + h;

    double v[8];
    #pragma unroll
    for (int p = 0; p < 8; p++) v[p] = wp[(size_t)p * H];

    for (int t0 = 0; t0 < T; t0 += 8) {
        double nv[8];
        const bool more = (t0 + 8) < T;
        const double* wn = wp + (size_t)(t0 + 8) * H;
        #pragma unroll
        for (int p = 0; p < 8; p++) nv[p] = more ? wn[(size_t)p * H] : 0.0;

        #pragma unroll
        for (int p = 0; p < 8; p++) {
            u = a * (u - s) + oma * v[p];           // exact ref op order
            s = (u - 1.0 > 0.0) ? 1.0 : 0.0;
            op[(size_t)(t0 + p) * H] = (float)s;
        }
        #pragma unroll
        for (int p = 0; p < 8; p++) v[p] = nv[p];
    }
}

extern "C" void kernel_launch(void* const* d_in, const int* in_sizes, int n_in,
                              void* d_out, int out_size, void* d_ws, size_t ws_size,
                              hipStream_t stream) {
    const float* x     = (const float*)d_in[0];   // [64,1000,1024]
    const float* W     = (const float*)d_in[1];   // [1024,1024]
    const float* alpha = (const float*)d_in[2];   // [1024]
    const float* u0    = (const float*)d_in[3];   // [64,1024]
    const float* s0    = (const float*)d_in[4];   // [64,1024]
    float* out = (float*)d_out;                   // [64,1000,1024] f32
    double* wx = (double*)d_ws;

    const int Bt = 64, T = 1000, I = 1024, H = 1024;

    // Adaptive chunk: largest Bc whose f64 Wx chunk fits the workspace.
    const size_t per_batch = (size_t)T * H * sizeof(double);   // 8.192 MB
    int Bc = 1;
    {
        const int cands[7] = {64, 32, 16, 8, 4, 2, 1};
        for (int c = 0; c < 7; c++) {
            if ((size_t)cands[c] * per_batch <= ws_size) { Bc = cands[c]; break; }
        }
    }

    for (int b0 = 0; b0 < Bt; b0 += Bc) {
        const int M = Bc * T;
        dim3 grid(H / TN, (M + TM - 1) / TM);
        gemm_f64_valu<<<grid, 256, 0, stream>>>(
            x + (size_t)b0 * T * I, W, wx, M, H, I);
        lif_scan_kernel<<<(Bc * H) / 256, 256, 0, stream>>>(
            wx, alpha, u0, s0, out, b0, T, H);
    }
}

// Round 7
// 2970.433 us; speedup vs baseline: 8.4162x; 8.4162x over previous
//
#include <hip/hip_runtime.h>

// LIF layer: Wx = x @ W^T (f64), then scan over T. B=64,T=1000,I=1024,H=1024.
// R7: GEMM restructured around the R2 finding that 8x8 register tiles are
//     LDS-throughput-bound (~68% ceiling). W is pre-transposed+converted to
//     f64 WdT[K][N] (8 MB ws) and read via wave-uniform scalar loads into
//     SGPRs (v_fma_f64 src0 = SGPR pair) -> W costs zero LDS/VALU. x stays on
//     the proven f32->f64 LDS staging; each lane reads ONE ds_read_b128 per kk
//     for 32 FMAs -> LDS ~10% utilized, FMA pipe is the limiter.
//     NO register-held prefetch across the FMA block (R6 spill lesson:
//     77 GB scratch writes). acc = 64 VGPRs. One barrier per k-tile.

#define TM 128
#define TN 64
#define TK 8
#define LDA 130   // As row stride (doubles); 130*8=1040 B = 16 B-aligned rows

// ---- pass 0: WdT[k][n] = (double)W[n][k] ----
__global__ __launch_bounds__(256) void transpose_w(
    const float* __restrict__ W, double* __restrict__ WdT)
{
    __shared__ float t[32][33];
    const int k0 = blockIdx.x * 32;
    const int n0 = blockIdx.y * 32;
    const int tx = threadIdx.x & 31;
    const int ty = threadIdx.x >> 5;   // 0..7
    #pragma unroll
    for (int i = 0; i < 4; i++)
        t[ty + 8 * i][tx] = W[(size_t)(n0 + ty + 8 * i) * 1024 + k0 + tx];
    __syncthreads();
    #pragma unroll
    for (int i = 0; i < 4; i++)
        WdT[(size_t)(k0 + ty + 8 * i) * 1024 + n0 + tx] = (double)t[tx][ty + 8 * i];
}

// ---- GEMM: C[M,N] = A[M,K](f32) * WdT[K,N](f64) ----
__global__ __launch_bounds__(256, 3) void gemm_f64_sgpr(
    const float* __restrict__ A,
    const double* __restrict__ WdT,
    double* __restrict__ C, int M, int N, int K)
{
    __shared__ double As[2][TK][LDA];   // 16,640 B

    const int tid  = threadIdx.x;
    const int lane = tid & 63;
    // wave-uniform n-base, forced into an SGPR so WdT reads become s_load
    const int nb = __builtin_amdgcn_readfirstlane(blockIdx.x * TN + (tid >> 6) * 16);
    const int tm = blockIdx.y * TM;

    // staging: thread t loads float4 of row r at k-quad kq
    const int kq = (tid & 1) * 4;   // 0 or 4
    const int r  = tid >> 1;        // 0..127

    double acc0[16], acc1[16];
    #pragma unroll
    for (int j = 0; j < 16; j++) { acc0[j] = 0.0; acc1[j] = 0.0; }

    const int ar = min(tm + r, M - 1);   // tail guard (loads only)
    const float* Ap = A + (size_t)ar * K + kq;

    // prologue: stage tile 0 into buf 0
    {
        const float4 a0 = *(const float4*)(Ap);
        As[0][kq + 0][r] = (double)a0.x; As[0][kq + 1][r] = (double)a0.y;
        As[0][kq + 2][r] = (double)a0.z; As[0][kq + 3][r] = (double)a0.w;
    }
    __syncthreads();

    // compute one k-tile from LDS buffer p, W from scalar loads
    auto compute_tile = [&](int p, int k0) {
        #pragma unroll
        for (int kk = 0; kk < TK; kk++) {
            const double* wr = WdT + (size_t)(k0 + kk) * N + nb;   // uniform
            const double2 a = *(const double2*)&As[p][kk][2 * lane];
            #pragma unroll
            for (int j = 0; j < 16; j++) {
                const double wj = wr[j];
                acc0[j] = fma(a.x, wj, acc0[j]);
                acc1[j] = fma(a.y, wj, acc1[j]);
            }
        }
    };

    const int NS = K / TK;   // 128 tiles
    for (int s = 0; s < NS - 1; ++s) {
        const int p = s & 1;
        // stage tile s+1 into the other buffer (loads consumed immediately —
        // no registers live across the FMA block)
        {
            const float4 a0 = *(const float4*)(Ap + (size_t)(s + 1) * TK);
            const int q = 1 - p;
            As[q][kq + 0][r] = (double)a0.x; As[q][kq + 1][r] = (double)a0.y;
            As[q][kq + 2][r] = (double)a0.z; As[q][kq + 3][r] = (double)a0.w;
        }
        compute_tile(p, s * TK);
        __syncthreads();
    }
    compute_tile((NS - 1) & 1, (NS - 1) * TK);

    // epilogue: lane covers rows m0, m0+1; 16 consecutive n-cols
    const int m0 = tm + 2 * lane;
    if (m0 < M) {
        double* Cr = C + (size_t)m0 * N + nb;
        #pragma unroll
        for (int j = 0; j < 8; j++)
            *(double2*)&Cr[2 * j] = double2{acc0[2 * j], acc0[2 * j + 1]};
    }
    if (m0 + 1 < M) {
        double* Cr = C + (size_t)(m0 + 1) * N + nb;
        #pragma unroll
        for (int j = 0; j < 8; j++)
            *(double2*)&Cr[2 * j] = double2{acc1[2 * j], acc1[2 * j + 1]};
    }
}

// ---- scan (unchanged, absmax-0.0 pedigree) ----
__global__ __launch_bounds__(256) void lif_scan_kernel(
    const double* __restrict__ Wx,
    const float* __restrict__ alpha,
    const float* __restrict__ u0,
    const float* __restrict__ s0,
    float* __restrict__ out,
    int b0, int T, int H)
{
    const int idx = blockIdx.x * blockDim.x + threadIdx.x;
    const int h  = idx & 1023;
    const int bl = idx >> 10;
    const int b  = b0 + bl;

    const double AMIN = 0.8187307530779818;   // exp(-1/5)
    const double AMAX = 0.9607894391523232;   // exp(-1/25)
    double a = (double)alpha[h];
    a = fmin(fmax(a, AMIN), AMAX);
    const double oma = 1.0 - a;

    double u = (double)u0[(size_t)b * H + h];
    double s = (double)s0[(size_t)b * H + h];

    const double* wp = Wx + (size_t)bl * T * H + h;
    float* op = out + (size_t)b * T * H + h;

    double v[8];
    #pragma unroll
    for (int p = 0; p < 8; p++) v[p] = wp[(size_t)p * H];

    for (int t0 = 0; t0 < T; t0 += 8) {
        double nv[8];
        const bool more = (t0 + 8) < T;
        const double* wn = wp + (size_t)(t0 + 8) * H;
        #pragma unroll
        for (int p = 0; p < 8; p++) nv[p] = more ? wn[(size_t)p * H] : 0.0;

        #pragma unroll
        for (int p = 0; p < 8; p++) {
            u = a * (u - s) + oma * v[p];           // exact ref op order
            s = (u - 1.0 > 0.0) ? 1.0 : 0.0;
            op[(size_t)(t0 + p) * H] = (float)s;
        }
        #pragma unroll
        for (int p = 0; p < 8; p++) v[p] = nv[p];
    }
}

extern "C" void kernel_launch(void* const* d_in, const int* in_sizes, int n_in,
                              void* d_out, int out_size, void* d_ws, size_t ws_size,
                              hipStream_t stream) {
    const float* x     = (const float*)d_in[0];   // [64,1000,1024]
    const float* W     = (const float*)d_in[1];   // [1024,1024]
    const float* alpha = (const float*)d_in[2];   // [1024]
    const float* u0    = (const float*)d_in[3];   // [64,1024]
    const float* s0    = (const float*)d_in[4];   // [64,1024]
    float* out = (float*)d_out;                   // [64,1000,1024] f32
    const int Bt = 64, T = 1000, I = 1024, H = 1024;

    // ws layout: [ WdT : 8 MiB f64 ][ wx : Bc*T*H f64 ]
    double* wdT = (double*)d_ws;
    const size_t wdT_bytes = (size_t)I * H * sizeof(double);   // 8 MiB
    double* wx = (double*)((char*)d_ws + wdT_bytes);
    const size_t avail = (ws_size > wdT_bytes) ? ws_size - wdT_bytes : 0;

    const size_t per_batch = (size_t)T * H * sizeof(double);   // 8.192 MB
    int Bc = 1;
    {
        const int cands[7] = {64, 32, 16, 8, 4, 2, 1};
        for (int c = 0; c < 7; c++) {
            if ((size_t)cands[c] * per_batch <= avail) { Bc = cands[c]; break; }
        }
    }

    transpose_w<<<dim3(1024 / 32, 1024 / 32), 256, 0, stream>>>(W, wdT);

    for (int b0 = 0; b0 < Bt; b0 += Bc) {
        const int M = Bc * T;
        dim3 grid(H / TN, (M + TM - 1) / TM);
        gemm_f64_sgpr<<<grid, 256, 0, stream>>>(
            x + (size_t)b0 * T * I, wdT, wx, M, H, I);
        lif_scan_kernel<<<(Bc * H) / 256, 256, 0, stream>>>(
            wx, alpha, u0, s0, out, b0, T, H);
    }
}